// Round 8
// baseline (199.013 us; speedup 1.0000x reference)
//
#include <hip/hip_runtime.h>
#include <cstdint>
#include <cstddef>

// MemoryEfficientAttention: B=2, S=2048, D=1024, H=16, Dh=64
// bf16 MFMA pipeline: fused cvt -> fused QKV gemm (V written transposed)
// -> flash attn v8 (mfma 32x32x16, 4 waves x 32 q-rows, K/V LDS dbuf,
// 1 barrier/tile) -> O-proj gemm.
// v8 rationale: R7 counters show attn is LDS-pipe-bound (16 b128 reads per
// 16 MFMA16). 32x32x16 doubles FLOP per fragment read -> 1.6x less LDS
// read traffic per unit work.

typedef unsigned short u16;
typedef unsigned int u32;
typedef __bf16 bf16x8 __attribute__((ext_vector_type(8)));
typedef float f32x4 __attribute__((ext_vector_type(4)));
typedef float f32x16 __attribute__((ext_vector_type(16)));

#define GLOAD_LDS16(gp, lp)                                                            \
  __builtin_amdgcn_global_load_lds((const __attribute__((address_space(1))) void*)(gp),\
                                   (__attribute__((address_space(3))) void*)(lp),      \
                                   16, 0, 0)

__device__ __forceinline__ u16 f2bf(float f) {  // round-to-nearest-even
  unsigned u = __builtin_bit_cast(unsigned, f);
  u = u + 0x7fffu + ((u >> 16) & 1u);
  return (u16)(u >> 16);
}

// two f32 -> packed bf16x2 (round-half-up), 3 VALU ops
__device__ __forceinline__ u32 pack_bf2(float a, float b) {
  u32 ua = __builtin_bit_cast(u32, a) + 0x8000u;
  u32 ub = __builtin_bit_cast(u32, b) + 0x8000u;
  return __builtin_amdgcn_perm(ub, ua, 0x07060302u);  // [b.hi16 | a.hi16]
}

// scale folded into Q: attn uses exp2, so fold log2(e) too
#define QSCALE 0.1803368801111204f   // 0.125 * log2(e)

// ---------------------------------------------------------------------------
// Fused fp32 -> bf16 convert for x + 4 weight matrices (1 launch).
// ---------------------------------------------------------------------------
__global__ void cvt_all(const float* __restrict__ x,
                        const float* __restrict__ wq, const float* __restrict__ wk,
                        const float* __restrict__ wv, const float* __restrict__ wo,
                        u16* __restrict__ xb, u16* __restrict__ wqb,
                        u16* __restrict__ wkb, u16* __restrict__ wvb,
                        u16* __restrict__ wob) {
  int bx = blockIdx.x;
  const float* s; u16* d; int off;
  if (bx < 2048)      { s = x;  d = xb;  off = bx; }
  else if (bx < 2560) { s = wq; d = wqb; off = bx - 2048; }
  else if (bx < 3072) { s = wk; d = wkb; off = bx - 2560; }
  else if (bx < 3584) { s = wv; d = wvb; off = bx - 3072; }
  else                { s = wo; d = wob; off = bx - 3584; }
  int i = off * 2048 + threadIdx.x * 8;
  float4 a = *(const float4*)(s + i);
  float4 b = *(const float4*)(s + i + 4);
  uint4 o;
  o.x = f2bf(a.x) | ((u32)f2bf(a.y) << 16);
  o.y = f2bf(a.z) | ((u32)f2bf(a.w) << 16);
  o.z = f2bf(b.x) | ((u32)f2bf(b.y) << 16);
  o.w = f2bf(b.z) | ((u32)f2bf(b.w) << 16);
  *(uint4*)(d + i) = o;
}

// ---------------------------------------------------------------------------
// bf16 MFMA GEMM (R3 version, verbatim): C[m][n] = sum_k A[m][k]*W[n][k]+b[n]
// 128x128 tile, BK=64, XOR-chunk-swizzled LDS via global_load_lds(16B).
// MODE 0: fused QKV (N=3072): Q scaled [B,H,S,Dh]; K [B,H,S,Dh];
//         V TRANSPOSED [B,H,Dh,S] (packed 8B stores, lane-contiguous in s).
// MODE 1: O-proj (N=1024), fp32 flat out (lane-contiguous dword stores).
// ---------------------------------------------------------------------------
template <int MODE>
__global__ __launch_bounds__(256, 3) void gemm_mfma(
    const u16* __restrict__ A,
    const u16* __restrict__ W0, const u16* __restrict__ W1, const u16* __restrict__ W2,
    const float* __restrict__ b0, const float* __restrict__ b1, const float* __restrict__ b2,
    u16* __restrict__ o0, u16* __restrict__ o1, u16* __restrict__ o2,
    float* __restrict__ oF)
{
  __shared__ __align__(16) u16 As[128 * 64];
  __shared__ __align__(16) u16 Bs[128 * 64];

  const int tid = threadIdx.x;
  const int w = tid >> 6, l = tid & 63;
  const int lane = l & 15, quad = l >> 4;
  const int wm = w >> 1, wn = w & 1;
  const int m0 = blockIdx.y * 128;
  const int n0g = blockIdx.x * 128;

  const int src = (MODE == 0) ? (n0g >> 10) : 0;
  const u16* Wsel = (MODE == 0) ? (src == 0 ? W0 : (src == 1 ? W1 : W2)) : W0;
  const float* bsel = (MODE == 0) ? (src == 0 ? b0 : (src == 1 ? b1 : b2)) : b0;
  const int n_base = (MODE == 0) ? (n0g & 1023) : n0g;

  const int c8 = ((l & 7) ^ (l >> 3)) * 8;

  f32x4 acc[4][4] = {};

  for (int kt = 0; kt < 1024; kt += 64) {
    __syncthreads();
    const u16* Ag = A + (size_t)m0 * 1024 + kt;
    const u16* Bg = Wsel + (size_t)n_base * 1024 + kt;
    #pragma unroll
    for (int i = 0; i < 4; ++i) {
      int rr = w * 32 + i * 8;
      GLOAD_LDS16(Ag + (size_t)(rr + (l >> 3)) * 1024 + c8, As + rr * 64);
      GLOAD_LDS16(Bg + (size_t)(rr + (l >> 3)) * 1024 + c8, Bs + rr * 64);
    }
    __syncthreads();

    bf16x8 af[4][2], bf[4][2];
    #pragma unroll
    for (int mf = 0; mf < 4; ++mf)
      #pragma unroll
      for (int ks = 0; ks < 2; ++ks) {
        af[mf][ks] = *(const bf16x8*)((const char*)As +
            (wm * 64 + mf * 16 + lane) * 128 + (((ks * 4 + quad) ^ (lane & 7)) * 16));
        bf[mf][ks] = *(const bf16x8*)((const char*)Bs +
            (wn * 64 + mf * 16 + lane) * 128 + (((ks * 4 + quad) ^ (lane & 7)) * 16));
      }
    #pragma unroll
    for (int ks = 0; ks < 2; ++ks)
      #pragma unroll
      for (int mf = 0; mf < 4; ++mf)
        #pragma unroll
        for (int nf = 0; nf < 4; ++nf)
          acc[mf][nf] = __builtin_amdgcn_mfma_f32_16x16x32_bf16(
              af[mf][ks], bf[nf][ks], acc[mf][nf], 0, 0, 0);
  }

  float bb[4];
  #pragma unroll
  for (int nf = 0; nf < 4; ++nf) bb[nf] = bsel[n_base + wn * 64 + nf * 16 + lane];

  u16* osel = (MODE == 0) ? (src == 0 ? o0 : (src == 1 ? o1 : o2)) : o0;

  #pragma unroll
  for (int mf = 0; mf < 4; ++mf) {
    int mb = m0 + wm * 64 + mf * 16 + quad * 4;
    #pragma unroll
    for (int nf = 0; nf < 4; ++nf) {
      int n_l = wn * 64 + nf * 16 + lane;
      if (MODE == 0 && src == 2) {
        float v0 = acc[mf][nf][0] + bb[nf];
        float v1 = acc[mf][nf][1] + bb[nf];
        float v2 = acc[mf][nf][2] + bb[nf];
        float v3 = acc[mf][nf][3] + bb[nf];
        int bi = mb >> 11, s = mb & 2047;
        int n_in = n_base + n_l;
        int h = n_in >> 6, dh = n_in & 63;
        uint2 pk = make_uint2(pack_bf2(v0, v1), pack_bf2(v2, v3));
        *(uint2*)(o2 + (((size_t)(bi * 16 + h) * 64 + dh) * 2048 + s)) = pk;
      } else {
        #pragma unroll
        for (int r = 0; r < 4; ++r) {
          float v = acc[mf][nf][r] + bb[nf];
          int m = mb + r;
          if (MODE == 0) {
            if (src == 0) v *= QSCALE;
            int bi = m >> 11, s = m & 2047;
            int n_in = n_base + n_l;
            int h = n_in >> 6, dh = n_in & 63;
            osel[(((size_t)(bi * 16 + h) * 2048 + s) << 6) + dh] = f2bf(v);
          } else {
            oF[(size_t)m * 1024 + n0g + n_l] = v;
          }
        }
      }
    }
  }
}

// ---------------------------------------------------------------------------
// Flash attention v8: mfma_f32_32x32x16_bf16, 4 waves x 32 q-rows.
// Block = (b,h) x 128 queries; 64-key tiles; K[64x64] and V^T[64x64] staged
// in LDS via global_load_lds, double-buffered, ONE barrier/tile (prefetch
// issued right after it -> drain covers a full compute phase).
// Layouts (32x32x16): A/B operand: row(col)=lane&31, k=(lane>>5)*8+j;
// C/D: col=lane&31, row=(reg&3)+8*(reg>>2)+4*(lane>>5).
// S^T = K·Q^T (A=K from LDS, B=Q in regs) -> lane's col = its q for the
// whole pipeline; reg-quads = 4 consecutive keys -> P packed (v_perm) as
// uint2 into chunk-XOR-swizzled wave-private LDS (128B row stride).
// PV: A=P (from Pw), B=V (key-contig rows of V^T tile). Softmax: bare exp2
// (0.125*log2e folded into Q; |s| bounded, validated R2+).
// LDS = 16 (K dbuf) + 16 (V dbuf) + 16 (P) = 48 KB; grid 512 = 2 blocks/CU.
// ---------------------------------------------------------------------------
__global__ __launch_bounds__(256, 2) void attn_mfma(
    const u16* __restrict__ Qg_, const u16* __restrict__ Kg_,
    const u16* __restrict__ VTg_, u16* __restrict__ Og)
{
  __shared__ __align__(16) u16 Ks[2][64 * 64];   // [key][dh]
  __shared__ __align__(16) u16 Vs[2][64 * 64];   // [dh][key]
  __shared__ __align__(16) u16 Ps[4][32 * 64];   // wave-private [q][key]

  const int tid = threadIdx.x;
  const int w = tid >> 6, l = tid & 63;
  const int q5 = l & 31;      // col lane index: q (S^T/P/O) or d (V B-frag)
  const int h  = l >> 5;      // half
  const int sw = q5 & 7;      // row-XOR swizzle key (row stride 128 B)
  const int bh = blockIdx.y;  // b*16 + h
  const int q0 = blockIdx.x * 128;

  const u16* Qg  = Qg_ + ((size_t)bh * 2048 + q0 + w * 32) * 64;
  const u16* Kg  = Kg_ + (size_t)bh * 2048 * 64;
  const u16* VTg = VTg_ + (size_t)bh * 64 * 2048;   // [dh][s]

  const int c8 = ((l & 7) ^ (l >> 3)) * 8;   // staging chunk swizzle
  const int lrow = l >> 3;
  const int rr = w * 16;      // this wave's 16 staging rows (2 glds insts)

  // Q B-frags (registers for the whole kernel): bq[s] = Q[q5][s*16+h*8 ..+7]
  bf16x8 bq[4];
  #pragma unroll
  for (int s = 0; s < 4; ++s)
    bq[s] = *(const bf16x8*)(Qg + (size_t)q5 * 64 + s * 16 + h * 8);

  // stage tile 0 into buffer 0
  #pragma unroll
  for (int i = 0; i < 2; ++i) {
    GLOAD_LDS16(Kg + (size_t)(rr + i * 8 + lrow) * 64 + c8,
                Ks[0] + (rr + i * 8) * 64);
    GLOAD_LDS16(VTg + (size_t)(rr + i * 8 + lrow) * 2048 + c8,
                Vs[0] + (rr + i * 8) * 64);
  }

  f32x16 oa[2] = {};
  float lsum = 0.f;
  u16* Pw = Ps[w];

  for (int kt = 0; kt < 32; ++kt) {
    const int buf = kt & 1;
    __syncthreads();  // tile kt staged (loads issued a full phase ago)

    // prefetch tile kt+1 into the freed buffer
    if (kt < 31) {
      #pragma unroll
      for (int i = 0; i < 2; ++i) {
        GLOAD_LDS16(Kg + (size_t)((kt + 1) * 64 + rr + i * 8 + lrow) * 64 + c8,
                    Ks[buf ^ 1] + (rr + i * 8) * 64);
        GLOAD_LDS16(VTg + (size_t)(rr + i * 8 + lrow) * 2048 + (kt + 1) * 64 + c8,
                    Vs[buf ^ 1] + (rr + i * 8) * 64);
      }
    }

    // S^T = K·Q^T: lane holds S[keys per reg][q=q5]; 2 key-subtiles x 4 dh-steps
    f32x16 sa[2] = {};
    #pragma unroll
    for (int s = 0; s < 4; ++s)
      #pragma unroll
      for (int kt2 = 0; kt2 < 2; ++kt2) {
        bf16x8 ak = *(const bf16x8*)((const char*)Ks[buf] +
            (kt2 * 32 + q5) * 128 + (((s * 2 + h) ^ sw) * 16));
        sa[kt2] = __builtin_amdgcn_mfma_f32_32x32x16_bf16(ak, bq[s], sa[kt2], 0, 0, 0);
      }

    // softmax numerator (bare exp2); packed P -> swizzled wave-private LDS
    // reg 4g+t = key kt2*32 + 8g + 4h + t  -> chunk c = kt2*4+g, sub-8B = h
    #pragma unroll
    for (int kt2 = 0; kt2 < 2; ++kt2)
      #pragma unroll
      for (int g = 0; g < 4; ++g) {
        float p0 = __builtin_amdgcn_exp2f(sa[kt2][4 * g + 0]);
        float p1 = __builtin_amdgcn_exp2f(sa[kt2][4 * g + 1]);
        float p2 = __builtin_amdgcn_exp2f(sa[kt2][4 * g + 2]);
        float p3 = __builtin_amdgcn_exp2f(sa[kt2][4 * g + 3]);
        lsum += (p0 + p1) + (p2 + p3);
        int c = kt2 * 4 + g;
        *(uint2*)((char*)Pw + q5 * 128 + ((c ^ sw) * 16) + 8 * h)
            = make_uint2(pack_bf2(p0, p1), pack_bf2(p2, p3));
      }

    // O += P·V : 4 key-steps x 2 d-subtiles (P wave-private: lgkm order ok)
    #pragma unroll
    for (int ks = 0; ks < 4; ++ks) {
      bf16x8 ap = *(const bf16x8*)((const char*)Pw +
          q5 * 128 + (((ks * 2 + h) ^ sw) * 16));
      #pragma unroll
      for (int dt = 0; dt < 2; ++dt) {
        bf16x8 bv = *(const bf16x8*)((const char*)Vs[buf] +
            (dt * 32 + q5) * 128 + (((ks * 2 + h) ^ sw) * 16));
        oa[dt] = __builtin_amdgcn_mfma_f32_32x32x16_bf16(ap, bv, oa[dt], 0, 0, 0);
      }
    }
  }

  // lane's lsum covers half the keys for q=q5; other half is in lane+/-32
  lsum += __shfl_xor(lsum, 32);

  // normalize + store to flat [b][s][h*64+d]; O row = (r&3)+8*(r>>2)+4h
  const int b = bh >> 4, hh = bh & 15;
  u16* Ob = Og + ((size_t)b * 2048 + q0 + w * 32) * 1024 + hh * 64;
  #pragma unroll
  for (int r = 0; r < 16; ++r) {
    int qrow = (r & 3) + 8 * (r >> 2) + 4 * h;
    float inv = 1.0f / __shfl(lsum, qrow);
    #pragma unroll
    for (int dt = 0; dt < 2; ++dt)
      Ob[(size_t)qrow * 1024 + dt * 32 + q5] = f2bf(oa[dt][r] * inv);
  }
}

// ---------------------------------------------------------------------------
// Workspace (u16): xb[4M] wq[1M] wk[1M] wv[1M] wo[1M] Q[4M] K[4M] VT[4M]
// AO[4M] = 24M u16 = 48 MB.
// ---------------------------------------------------------------------------
extern "C" void kernel_launch(void* const* d_in, const int* in_sizes, int n_in,
                              void* d_out, int out_size, void* d_ws, size_t ws_size,
                              hipStream_t stream)
{
  (void)in_sizes; (void)n_in; (void)out_size; (void)ws_size;
  const float* x  = (const float*)d_in[0];
  const float* Wq = (const float*)d_in[1];
  const float* bq = (const float*)d_in[2];
  const float* Wk = (const float*)d_in[3];
  const float* bk = (const float*)d_in[4];
  const float* Wv = (const float*)d_in[5];
  const float* bv = (const float*)d_in[6];
  const float* Wo = (const float*)d_in[7];
  const float* bo = (const float*)d_in[8];
  float* y = (float*)d_out;

  const size_t NM = (size_t)4096 * 1024;
  u16* xb  = (u16*)d_ws;
  u16* wqb = xb + NM;
  u16* wkb = wqb + 1024 * 1024;
  u16* wvb = wkb + 1024 * 1024;
  u16* wob = wvb + 1024 * 1024;
  u16* Qb  = wob + 1024 * 1024;
  u16* Kb  = Qb + NM;
  u16* VTb = Kb + NM;
  u16* AOb = VTb + NM;

  cvt_all<<<4096, 256, 0, stream>>>(x, Wq, Wk, Wv, Wo, xb, wqb, wkb, wvb, wob);

  gemm_mfma<0><<<dim3(24, 32), 256, 0, stream>>>(
      xb, wqb, wkb, wvb, bq, bk, bv, Qb, Kb, VTb, nullptr);

  attn_mfma<<<dim3(16, 32), 256, 0, stream>>>(Qb, Kb, VTb, AOb);

  gemm_mfma<1><<<dim3(8, 32), 256, 0, stream>>>(
      AOb, wob, nullptr, nullptr, bo, nullptr, nullptr,
      nullptr, nullptr, nullptr, y);
}

// Round 9
// 183.831 us; speedup vs baseline: 1.0826x; 1.0826x over previous
//
#include <hip/hip_runtime.h>
#include <cstdint>
#include <cstddef>

// MemoryEfficientAttention: B=2, S=2048, D=1024, H=16, Dh=64
// bf16 MFMA pipeline: fused cvt -> fused QKV gemm (V written transposed)
// -> flash attn v9 (8 waves = 4 pairs; pair owns 32 q-rows, waves split the
// key dim 32/32; 10 b128 LDS reads per wave-tile vs R7's 18) -> O-proj gemm.
// R7 post-mortem: attn was exactly LDS-throughput-bound (131k cyc/CU model =
// 55 us measured). v9 cuts LDS reads/FLOP 1.8x with the SAME (empirically
// conflict-free) 16-row chunk-XOR addressing; R8's 32-row pattern conflicted.

typedef unsigned short u16;
typedef unsigned int u32;
typedef __bf16 bf16x8 __attribute__((ext_vector_type(8)));
typedef float f32x4 __attribute__((ext_vector_type(4)));

#define GLOAD_LDS16(gp, lp)                                                            \
  __builtin_amdgcn_global_load_lds((const __attribute__((address_space(1))) void*)(gp),\
                                   (__attribute__((address_space(3))) void*)(lp),      \
                                   16, 0, 0)

__device__ __forceinline__ u16 f2bf(float f) {  // round-to-nearest-even
  unsigned u = __builtin_bit_cast(unsigned, f);
  u = u + 0x7fffu + ((u >> 16) & 1u);
  return (u16)(u >> 16);
}

// two f32 -> packed bf16x2 (round-half-up), 3 VALU ops
__device__ __forceinline__ u32 pack_bf2(float a, float b) {
  u32 ua = __builtin_bit_cast(u32, a) + 0x8000u;
  u32 ub = __builtin_bit_cast(u32, b) + 0x8000u;
  return __builtin_amdgcn_perm(ub, ua, 0x07060302u);  // [b.hi16 | a.hi16]
}

// scale folded into Q: attn uses exp2, so fold log2(e) too
#define QSCALE 0.1803368801111204f   // 0.125 * log2(e)

// ---------------------------------------------------------------------------
// Fused fp32 -> bf16 convert for x + 4 weight matrices (1 launch).
// ---------------------------------------------------------------------------
__global__ void cvt_all(const float* __restrict__ x,
                        const float* __restrict__ wq, const float* __restrict__ wk,
                        const float* __restrict__ wv, const float* __restrict__ wo,
                        u16* __restrict__ xb, u16* __restrict__ wqb,
                        u16* __restrict__ wkb, u16* __restrict__ wvb,
                        u16* __restrict__ wob) {
  int bx = blockIdx.x;
  const float* s; u16* d; int off;
  if (bx < 2048)      { s = x;  d = xb;  off = bx; }
  else if (bx < 2560) { s = wq; d = wqb; off = bx - 2048; }
  else if (bx < 3072) { s = wk; d = wkb; off = bx - 2560; }
  else if (bx < 3584) { s = wv; d = wvb; off = bx - 3072; }
  else                { s = wo; d = wob; off = bx - 3584; }
  int i = off * 2048 + threadIdx.x * 8;
  float4 a = *(const float4*)(s + i);
  float4 b = *(const float4*)(s + i + 4);
  uint4 o;
  o.x = f2bf(a.x) | ((u32)f2bf(a.y) << 16);
  o.y = f2bf(a.z) | ((u32)f2bf(a.w) << 16);
  o.z = f2bf(b.x) | ((u32)f2bf(b.y) << 16);
  o.w = f2bf(b.z) | ((u32)f2bf(b.w) << 16);
  *(uint4*)(d + i) = o;
}

// ---------------------------------------------------------------------------
// bf16 MFMA GEMM (R3 version, verbatim): C[m][n] = sum_k A[m][k]*W[n][k]+b[n]
// 128x128 tile, BK=64, XOR-chunk-swizzled LDS via global_load_lds(16B).
// MODE 0: fused QKV (N=3072): Q scaled [B,H,S,Dh]; K [B,H,S,Dh];
//         V TRANSPOSED [B,H,Dh,S] (packed 8B stores, lane-contiguous in s).
// MODE 1: O-proj (N=1024), fp32 flat out (lane-contiguous dword stores).
// ---------------------------------------------------------------------------
template <int MODE>
__global__ __launch_bounds__(256, 3) void gemm_mfma(
    const u16* __restrict__ A,
    const u16* __restrict__ W0, const u16* __restrict__ W1, const u16* __restrict__ W2,
    const float* __restrict__ b0, const float* __restrict__ b1, const float* __restrict__ b2,
    u16* __restrict__ o0, u16* __restrict__ o1, u16* __restrict__ o2,
    float* __restrict__ oF)
{
  __shared__ __align__(16) u16 As[128 * 64];
  __shared__ __align__(16) u16 Bs[128 * 64];

  const int tid = threadIdx.x;
  const int w = tid >> 6, l = tid & 63;
  const int lane = l & 15, quad = l >> 4;
  const int wm = w >> 1, wn = w & 1;
  const int m0 = blockIdx.y * 128;
  const int n0g = blockIdx.x * 128;

  const int src = (MODE == 0) ? (n0g >> 10) : 0;
  const u16* Wsel = (MODE == 0) ? (src == 0 ? W0 : (src == 1 ? W1 : W2)) : W0;
  const float* bsel = (MODE == 0) ? (src == 0 ? b0 : (src == 1 ? b1 : b2)) : b0;
  const int n_base = (MODE == 0) ? (n0g & 1023) : n0g;

  const int c8 = ((l & 7) ^ (l >> 3)) * 8;

  f32x4 acc[4][4] = {};

  for (int kt = 0; kt < 1024; kt += 64) {
    __syncthreads();
    const u16* Ag = A + (size_t)m0 * 1024 + kt;
    const u16* Bg = Wsel + (size_t)n_base * 1024 + kt;
    #pragma unroll
    for (int i = 0; i < 4; ++i) {
      int rr = w * 32 + i * 8;
      GLOAD_LDS16(Ag + (size_t)(rr + (l >> 3)) * 1024 + c8, As + rr * 64);
      GLOAD_LDS16(Bg + (size_t)(rr + (l >> 3)) * 1024 + c8, Bs + rr * 64);
    }
    __syncthreads();

    bf16x8 af[4][2], bf[4][2];
    #pragma unroll
    for (int mf = 0; mf < 4; ++mf)
      #pragma unroll
      for (int ks = 0; ks < 2; ++ks) {
        af[mf][ks] = *(const bf16x8*)((const char*)As +
            (wm * 64 + mf * 16 + lane) * 128 + (((ks * 4 + quad) ^ (lane & 7)) * 16));
        bf[mf][ks] = *(const bf16x8*)((const char*)Bs +
            (wn * 64 + mf * 16 + lane) * 128 + (((ks * 4 + quad) ^ (lane & 7)) * 16));
      }
    #pragma unroll
    for (int ks = 0; ks < 2; ++ks)
      #pragma unroll
      for (int mf = 0; mf < 4; ++mf)
        #pragma unroll
        for (int nf = 0; nf < 4; ++nf)
          acc[mf][nf] = __builtin_amdgcn_mfma_f32_16x16x32_bf16(
              af[mf][ks], bf[nf][ks], acc[mf][nf], 0, 0, 0);
  }

  float bb[4];
  #pragma unroll
  for (int nf = 0; nf < 4; ++nf) bb[nf] = bsel[n_base + wn * 64 + nf * 16 + lane];

  u16* osel = (MODE == 0) ? (src == 0 ? o0 : (src == 1 ? o1 : o2)) : o0;

  #pragma unroll
  for (int mf = 0; mf < 4; ++mf) {
    int mb = m0 + wm * 64 + mf * 16 + quad * 4;
    #pragma unroll
    for (int nf = 0; nf < 4; ++nf) {
      int n_l = wn * 64 + nf * 16 + lane;
      if (MODE == 0 && src == 2) {
        float v0 = acc[mf][nf][0] + bb[nf];
        float v1 = acc[mf][nf][1] + bb[nf];
        float v2 = acc[mf][nf][2] + bb[nf];
        float v3 = acc[mf][nf][3] + bb[nf];
        int bi = mb >> 11, s = mb & 2047;
        int n_in = n_base + n_l;
        int h = n_in >> 6, dh = n_in & 63;
        uint2 pk = make_uint2(pack_bf2(v0, v1), pack_bf2(v2, v3));
        *(uint2*)(o2 + (((size_t)(bi * 16 + h) * 64 + dh) * 2048 + s)) = pk;
      } else {
        #pragma unroll
        for (int r = 0; r < 4; ++r) {
          float v = acc[mf][nf][r] + bb[nf];
          int m = mb + r;
          if (MODE == 0) {
            if (src == 0) v *= QSCALE;
            int bi = m >> 11, s = m & 2047;
            int n_in = n_base + n_l;
            int h = n_in >> 6, dh = n_in & 63;
            osel[(((size_t)(bi * 16 + h) * 2048 + s) << 6) + dh] = f2bf(v);
          } else {
            oF[(size_t)m * 1024 + n0g + n_l] = v;
          }
        }
      }
    }
  }
}

// ---------------------------------------------------------------------------
// Flash attention v9: 512 threads = 8 waves = 4 PAIRS. Pair g owns q rows
// g*32..g*32+31; within a pair, wave kh=0 handles keys 0..31 of every tile,
// kh=1 keys 32..63. Per wave-tile (32q x 32key x 64d): ak 4 + ap 2 + bv 4
// = 10 ds_read_b128 (K-frags amortized over 2 q-frags; 32 keys = one
// mfma16 K-depth so ap/bv have no ks dimension). All LDS addressing keeps
// the R3/R7-proven form: 16-row frags (row = lane mod 16), chunk-XOR
// c ^ (lane&7), 128 B row stride. P buffers are PAIR-shared: each wave
// writes/reads only its kh's chunk half (disjoint bytes, no race, no sync).
// Partial O and lsum combined once at the end via LDS aliased over K/V
// (union), 2 extra barriers. LDS = 16+16+16 = 48 KB -> 2 blocks/CU ->
// 16 waves/CU. Softmax: bare exp2 (0.125*log2e folded into Q).
// ---------------------------------------------------------------------------
union SMemU {
  struct {
    u16 K[2][64 * 64];   // [key][dh]
    u16 V[2][64 * 64];   // [dh][key]
    u16 P[4][32 * 64];   // per-pair [q][key], 128 B rows
  } m;
  struct {
    float O[4][32 * 64]; // per-pair partial O [q][d]
    float L[4][32];      // per-pair partial lsum
  } f;
};

__global__ __launch_bounds__(512, 4) void attn_mfma(
    const u16* __restrict__ Qg_, const u16* __restrict__ Kg_,
    const u16* __restrict__ VTg_, u16* __restrict__ Og)
{
  __shared__ __align__(16) SMemU sm;

  const int tid = threadIdx.x;
  const int w = tid >> 6, l = tid & 63;
  const int lane = l & 15, quad = l >> 4;
  const int g = w >> 1;       // pair index: q rows g*32..+31
  const int kh = w & 1;       // key half: keys kh*32..+31 of each tile
  const int bh = blockIdx.y;  // b*16 + h
  const int q0 = blockIdx.x * 128;

  const u16* Qg  = Qg_ + ((size_t)bh * 2048 + q0 + g * 32) * 64;
  const u16* Kg  = Kg_ + (size_t)bh * 2048 * 64;
  const u16* VTg = VTg_ + (size_t)bh * 64 * 2048;   // [dh][s]

  const int c8 = ((l & 7) ^ (l >> 3)) * 8;   // staging chunk swizzle
  const int lrow = l >> 3;
  const int rr = w * 8;       // this wave's 8 staging rows (1 glds per tensor)

  // Q B-frags (registers for the whole kernel)
  bf16x8 bq[2][2];
  #pragma unroll
  for (int qf = 0; qf < 2; ++qf)
    #pragma unroll
    for (int ks = 0; ks < 2; ++ks)
      bq[qf][ks] = *(const bf16x8*)(Qg +
          (size_t)(qf * 16 + lane) * 64 + ks * 32 + quad * 8);

  // stage tile 0 into buffer 0
  GLOAD_LDS16(Kg + (size_t)(rr + lrow) * 64 + c8, sm.m.K[0] + rr * 64);
  GLOAD_LDS16(VTg + (size_t)(rr + lrow) * 2048 + c8, sm.m.V[0] + rr * 64);

  f32x4 oa[2][4] = {};
  float lsum[2] = {0.f, 0.f};
  u16* Pp = sm.m.P[g];

  for (int kt = 0; kt < 32; ++kt) {
    const int buf = kt & 1;
    __syncthreads();  // tile kt staged (loads issued a full phase ago)

    // prefetch tile kt+1 into the freed buffer
    if (kt < 31) {
      GLOAD_LDS16(Kg + (size_t)((kt + 1) * 64 + rr + lrow) * 64 + c8,
                  sm.m.K[buf ^ 1] + rr * 64);
      GLOAD_LDS16(VTg + (size_t)(rr + lrow) * 2048 + (kt + 1) * 64 + c8,
                  sm.m.V[buf ^ 1] + rr * 64);
    }

    // S^T = K·Q^T over this wave's 32 keys:
    // sa[kf][qf]: key = kh*32 + kf*16 + quad*4 + r, q = qf*16 + lane
    f32x4 sa[2][2] = {};
    #pragma unroll
    for (int ks = 0; ks < 2; ++ks) {
      bf16x8 ak[2];
      #pragma unroll
      for (int kf = 0; kf < 2; ++kf)
        ak[kf] = *(const bf16x8*)((const char*)sm.m.K[buf] +
            (kh * 32 + kf * 16 + lane) * 128 + (((ks * 4 + quad) ^ (lane & 7)) * 16));
      #pragma unroll
      for (int kf = 0; kf < 2; ++kf)
        #pragma unroll
        for (int qf = 0; qf < 2; ++qf)
          sa[kf][qf] = __builtin_amdgcn_mfma_f32_16x16x32_bf16(
              ak[kf], bq[qf][ks], sa[kf][qf], 0, 0, 0);
    }

    // softmax numerator (bare exp2); packed P -> pair-shared swizzled LDS.
    // logical chunk = kh*4 + kf*2 + (quad>>1), sub-8B = quad&1
    #pragma unroll
    for (int qf = 0; qf < 2; ++qf) {
      int qrow = qf * 16 + lane;
      #pragma unroll
      for (int kf = 0; kf < 2; ++kf) {
        float p0 = __builtin_amdgcn_exp2f(sa[kf][qf][0]);
        float p1 = __builtin_amdgcn_exp2f(sa[kf][qf][1]);
        float p2 = __builtin_amdgcn_exp2f(sa[kf][qf][2]);
        float p3 = __builtin_amdgcn_exp2f(sa[kf][qf][3]);
        lsum[qf] += (p0 + p1) + (p2 + p3);
        int c = kh * 4 + kf * 2 + (quad >> 1);
        *(uint2*)((char*)Pp + qrow * 128 + ((c ^ (lane & 7)) * 16) + (quad & 1) * 8)
            = make_uint2(pack_bf2(p0, p1), pack_bf2(p2, p3));
      }
    }

    // O += P·V over this wave's 32 keys (single mfma16 K-depth):
    // ap: A=P[q][key], k = kh*32 + quad*8 + j -> chunk kh*4 + quad
    // bv: B=V^T[d][key], same k mapping
    {
      bf16x8 bv[4];
      #pragma unroll
      for (int df = 0; df < 4; ++df)
        bv[df] = *(const bf16x8*)((const char*)sm.m.V[buf] +
            (df * 16 + lane) * 128 + (((kh * 4 + quad) ^ (lane & 7)) * 16));
      bf16x8 ap[2];
      #pragma unroll
      for (int qf = 0; qf < 2; ++qf)
        ap[qf] = *(const bf16x8*)((const char*)Pp +
            (qf * 16 + lane) * 128 + (((kh * 4 + quad) ^ (lane & 7)) * 16));
      #pragma unroll
      for (int qf = 0; qf < 2; ++qf)
        #pragma unroll
        for (int df = 0; df < 4; ++df)
          oa[qf][df] = __builtin_amdgcn_mfma_f32_16x16x32_bf16(
              ap[qf], bv[df], oa[qf][df], 0, 0, 0);
    }
  }

  // reduce lsum across quads: every lane then holds the wave-partial sum
  // for q = qf*16 + (l&15)
  #pragma unroll
  for (int qf = 0; qf < 2; ++qf) {
    lsum[qf] += __shfl_xor(lsum[qf], 16);
    lsum[qf] += __shfl_xor(lsum[qf], 32);
  }

  // ---- pair combine: kh=1 wave publishes partials, kh=0 wave merges ----
  __syncthreads();  // main-loop LDS reads complete; safe to alias via union
  if (kh == 1) {
    #pragma unroll
    for (int qf = 0; qf < 2; ++qf)
      #pragma unroll
      for (int df = 0; df < 4; ++df)
        #pragma unroll
        for (int r = 0; r < 4; ++r)
          sm.f.O[g][(qf * 16 + quad * 4 + r) * 64 + df * 16 + lane] = oa[qf][df][r];
    if (l < 16) {
      sm.f.L[g][l] = lsum[0];
      sm.f.L[g][16 + l] = lsum[1];
    }
  }
  __syncthreads();
  if (kh == 0) {
    const int b = bh >> 4, hh = bh & 15;
    u16* Ob = Og + ((size_t)b * 2048 + q0 + g * 32) * 1024 + hh * 64;
    float ltot[2];
    #pragma unroll
    for (int qf = 0; qf < 2; ++qf)
      ltot[qf] = lsum[qf] + sm.f.L[g][qf * 16 + lane];
    #pragma unroll
    for (int qf = 0; qf < 2; ++qf)
      #pragma unroll
      for (int r = 0; r < 4; ++r) {
        float inv = 1.0f / __shfl(ltot[qf], quad * 4 + r, 16);
        int qrow = qf * 16 + quad * 4 + r;
        #pragma unroll
        for (int df = 0; df < 4; ++df) {
          float v = oa[qf][df][r] + sm.f.O[g][qrow * 64 + df * 16 + lane];
          Ob[(size_t)qrow * 1024 + df * 16 + lane] = f2bf(v * inv);
        }
      }
  }
}

// ---------------------------------------------------------------------------
// Workspace (u16): xb[4M] wq[1M] wk[1M] wv[1M] wo[1M] Q[4M] K[4M] VT[4M]
// AO[4M] = 24M u16 = 48 MB.
// ---------------------------------------------------------------------------
extern "C" void kernel_launch(void* const* d_in, const int* in_sizes, int n_in,
                              void* d_out, int out_size, void* d_ws, size_t ws_size,
                              hipStream_t stream)
{
  (void)in_sizes; (void)n_in; (void)out_size; (void)ws_size;
  const float* x  = (const float*)d_in[0];
  const float* Wq = (const float*)d_in[1];
  const float* bq = (const float*)d_in[2];
  const float* Wk = (const float*)d_in[3];
  const float* bk = (const float*)d_in[4];
  const float* Wv = (const float*)d_in[5];
  const float* bv = (const float*)d_in[6];
  const float* Wo = (const float*)d_in[7];
  const float* bo = (const float*)d_in[8];
  float* y = (float*)d_out;

  const size_t NM = (size_t)4096 * 1024;
  u16* xb  = (u16*)d_ws;
  u16* wqb = xb + NM;
  u16* wkb = wqb + 1024 * 1024;
  u16* wvb = wkb + 1024 * 1024;
  u16* wob = wvb + 1024 * 1024;
  u16* Qb  = wob + 1024 * 1024;
  u16* Kb  = Qb + NM;
  u16* VTb = Kb + NM;
  u16* AOb = VTb + NM;

  cvt_all<<<4096, 256, 0, stream>>>(x, Wq, Wk, Wv, Wo, xb, wqb, wkb, wvb, wob);

  gemm_mfma<0><<<dim3(24, 32), 256, 0, stream>>>(
      xb, wqb, wkb, wvb, bq, bk, bv, Qb, Kb, VTb, nullptr);

  attn_mfma<<<dim3(16, 32), 512, 0, stream>>>(Qb, Kb, VTb, AOb);

  gemm_mfma<1><<<dim3(8, 32), 256, 0, stream>>>(
      AOb, wob, nullptr, nullptr, bo, nullptr, nullptr,
      nullptr, nullptr, nullptr, y);
}